// Round 16
// baseline (413.021 us; speedup 1.0000x reference)
//
#include <hip/hip_runtime.h>

#define NN 16384
#define NE 262144
#define CAP 64               // slots per target; in-degree ~Poisson(16); CAP=64 validated r15 (absmax=0)
#define WSTR 324             // LDS stride for [o][k] weight tile (k=0..319; 324%32=4 -> worst 4-way)

// ============================================================================
// 4 dispatches: zero -> scatter(tgt slots) -> layer1 -> layer2(+pool+head)
// layer kernel (per block = 4 targets, wave per target):
//   edge loop: T[s,i] += e[ed,s]*h[src,i]  (e via float4 broadcast loads, h from
//              2MB L2-resident table; halves process alternating edges)
//   epilogue:  in-LDS GEMM  agg[t,o] = b[o] + sum_k Trow[t,k]*W[k,o]
//              where Trow = [T(288) | h_t(32)], W = [Wk|bk|root] staged [o][k].
// ============================================================================

__global__ __launch_bounds__(256) void zero_kernel(int* __restrict__ cnt,
                                                   float* __restrict__ pooled,
                                                   int* __restrict__ ticket)
{
    int i = blockIdx.x * blockDim.x + threadIdx.x;
    if (i < NN) cnt[i] = 0;
    if (i < 256) pooled[i] = 0.0f;       // 8 XCD replicas x 32
    if (i == 256) *ticket = 0;
}

__global__ __launch_bounds__(256) void scatter_kernel(
    const int* __restrict__ src, const int* __restrict__ tgt,
    int* __restrict__ cnt, int2* __restrict__ pair)
{
    int i = blockIdx.x * blockDim.x + threadIdx.x;
    if (i < NE) {
        int t = tgt[i];
        int idx = atomicAdd(&cnt[t], 1);
        if (idx < CAP)
            pair[(size_t)t * CAP + idx] = make_int2(src[i], i);
    }
}

__global__ __launch_bounds__(256) void layer_kernel(
    const float* __restrict__ hin, int stride, int apply_relu,
    const float* __restrict__ efeat, const int2* __restrict__ pair,
    const int* __restrict__ cnt,
    const float* __restrict__ Wk, const float* __restrict__ bk,
    const float* __restrict__ root, const float* __restrict__ bvec,
    float* __restrict__ aggout, int do_pool,
    float* __restrict__ pooled, int* __restrict__ ticket,
    const float* __restrict__ Wd, const float* __restrict__ bd,
    float* __restrict__ out)
{
    __shared__ float wldsT[32 * WSTR];   // [o][k], k in [0,320)
    __shared__ float tlds[4][WSTR];      // [t_local][k], k in [0,320)
    __shared__ float scr[4][32];

    // ---- stage combined weights, LDS-transposed: wldsT[o][k] ----
    // k<256: Wk[s=k>>5][ (k&31)*32+o ]; k in [256,288): bk; k in [288,320): root
    for (int idx = threadIdx.x; idx < 320 * 32; idx += 256) {
        int k = idx >> 5, o = idx & 31;
        float v;
        if (k < 256)      v = Wk[(k >> 5) * 1024 + (k & 31) * 32 + o];
        else if (k < 288) v = bk[(k - 256) * 32 + o];
        else              v = root[(k - 288) * 32 + o];
        wldsT[o * WSTR + k] = v;
    }

    // ---- edge phase: wave per target, halves on alternating edges ----
    int wid  = threadIdx.x >> 6;
    int lane = threadIdx.x & 63;
    int i    = lane & 31;
    int hi01 = lane >> 5;
    int t    = blockIdx.x * 4 + wid;

    int n = cnt[t];
    if (n > CAP) n = CAP;
    const int2* ps = pair + (size_t)t * CAP;

    float T[9] = {0.f, 0.f, 0.f, 0.f, 0.f, 0.f, 0.f, 0.f, 0.f};

    int nh = n >> 1;
#pragma unroll 2
    for (int jj = 0; jj < nh; ++jj) {
        int2 p = ps[jj * 2 + hi01];
        float hv = hin[(size_t)p.x * stride + i];
        if (apply_relu) hv = fmaxf(hv, 0.0f);
        const float4* pe = (const float4*)(efeat + (size_t)p.y * 8);
        float4 ea = pe[0];
        float4 eb = pe[1];
        T[0] = fmaf(ea.x, hv, T[0]);
        T[1] = fmaf(ea.y, hv, T[1]);
        T[2] = fmaf(ea.z, hv, T[2]);
        T[3] = fmaf(ea.w, hv, T[3]);
        T[4] = fmaf(eb.x, hv, T[4]);
        T[5] = fmaf(eb.y, hv, T[5]);
        T[6] = fmaf(eb.z, hv, T[6]);
        T[7] = fmaf(eb.w, hv, T[7]);
        T[8] += hv;
    }
    if ((n & 1) && hi01 == 0) {          // odd tail: low half only
        int2 p = ps[n - 1];
        float hv = hin[(size_t)p.x * stride + i];
        if (apply_relu) hv = fmaxf(hv, 0.0f);
        const float4* pe = (const float4*)(efeat + (size_t)p.y * 8);
        float4 ea = pe[0];
        float4 eb = pe[1];
        T[0] = fmaf(ea.x, hv, T[0]);
        T[1] = fmaf(ea.y, hv, T[1]);
        T[2] = fmaf(ea.z, hv, T[2]);
        T[3] = fmaf(ea.w, hv, T[3]);
        T[4] = fmaf(eb.x, hv, T[4]);
        T[5] = fmaf(eb.y, hv, T[5]);
        T[6] = fmaf(eb.z, hv, T[6]);
        T[7] = fmaf(eb.w, hv, T[7]);
        T[8] += hv;
    }

    // combine halves (9 shfl per TARGET), write T row + h_t row to LDS
#pragma unroll
    for (int s = 0; s < 9; ++s) T[s] += __shfl_xor(T[s], 32, 64);

    float ht = hin[(size_t)t * stride + i];
    if (apply_relu) ht = fmaxf(ht, 0.0f);
    if (hi01 == 0) {
#pragma unroll
        for (int s = 0; s < 9; ++s) tlds[wid][s * 32 + i] = T[s];
        tlds[wid][288 + i] = ht;
    }
    __syncthreads();

    // ---- epilogue GEMM: thread = (o, tg, kh); 160 k-steps each ----
    int o  = threadIdx.x & 31;
    int g  = threadIdx.x >> 5;           // 0..7
    int tg = g & 3;
    int kh = g >> 2;

    float acc = 0.0f;
    const float4* t4 = (const float4*)&tlds[tg][kh * 160];
    const float4* w4 = (const float4*)&wldsT[o * WSTR + kh * 160];
#pragma unroll
    for (int q = 0; q < 40; ++q) {
        float4 a = t4[q];                // same-addr broadcast (free)
        float4 b = w4[q];
        acc = fmaf(a.x, b.x, acc);
        acc = fmaf(a.y, b.y, acc);
        acc = fmaf(a.z, b.z, acc);
        acc = fmaf(a.w, b.w, acc);
    }

    if (kh == 1) scr[tg][o] = acc;
    __syncthreads();
    float v = 0.0f;
    if (kh == 0) v = acc + scr[tg][o] + bvec[o];

    if (!do_pool) {
        if (kh == 0)
            aggout[(size_t)(blockIdx.x * 4 + tg) * 32 + o] = v;
    } else {
        __syncthreads();
        if (kh == 0) scr[tg][o] = fmaxf(v, 0.0f);
        __syncthreads();
        if (g == 0) {
            float rs = scr[0][o] + scr[1][o] + scr[2][o] + scr[3][o];
            atomicAdd(&pooled[(blockIdx.x & 7) * 32 + o], rs);
        }
        __threadfence();
        __shared__ int lastf;
        if (threadIdx.x == 0)
            lastf = (atomicAdd(ticket, 1) == (int)gridDim.x - 1) ? 1 : 0;
        __syncthreads();
        if (lastf && threadIdx.x < 64) {
            float pv = 0.0f;
            if (threadIdx.x < 32) {
#pragma unroll
                for (int r = 0; r < 8; ++r)
                    pv += atomicAdd(&pooled[r * 32 + threadIdx.x], 0.0f);
                pv *= Wd[threadIdx.x];
            }
#pragma unroll
            for (int k = 32; k >= 1; k >>= 1) pv += __shfl_xor(pv, k, 64);
            if (threadIdx.x == 0) out[0] = fmaxf(pv + bd[0], 0.0f);
        }
    }
}

// ============================================================================
extern "C" void kernel_launch(void* const* d_in, const int* in_sizes, int n_in,
                              void* d_out, int out_size, void* d_ws, size_t ws_size,
                              hipStream_t stream)
{
    const float* x     = (const float*)d_in[0];
    const int*   src   = (const int*)d_in[1];
    const int*   tgt   = (const int*)d_in[2];
    const float* e     = (const float*)d_in[3];
    const float* Wk1   = (const float*)d_in[4];
    const float* bk1   = (const float*)d_in[5];
    const float* root1 = (const float*)d_in[6];
    const float* b1    = (const float*)d_in[7];
    const float* Wk2   = (const float*)d_in[8];
    const float* bk2   = (const float*)d_in[9];
    const float* root2 = (const float*)d_in[10];
    const float* b2    = (const float*)d_in[11];
    const float* Wd    = (const float*)d_in[12];
    const float* bd    = (const float*)d_in[13];
    float* out = (float*)d_out;

    // workspace: agg1 (2MB) | pooled 8x32 + ticket (256B) | cnt (64KB) | pair (8MB)
    char* ws = (char*)d_ws;
    size_t off = 0;
    float* agg1   = (float*)(ws + off); off += (size_t)NN * 32 * 4;
    float* pooled = (float*)(ws + off);
    int*   ticket = (int*)  (ws + off + 256 * 4); off += 256 * 4 + 256;
    int*   cnt    = (int*)  (ws + off); off += (size_t)NN * 4;
    int2*  pair   = (int2*) (ws + off); off += (size_t)NN * CAP * 8;

    zero_kernel<<<64, 256, 0, stream>>>(cnt, pooled, ticket);
    scatter_kernel<<<NE / 256, 256, 0, stream>>>(src, tgt, cnt, pair);

    // layer 1: h = x[:, :32] (stride 33, no relu) -> agg1
    layer_kernel<<<NN / 4, 256, 0, stream>>>(x, 33, 0, e, pair, cnt,
                                             Wk1, bk1, root1, b1,
                                             agg1, 0, pooled, ticket, Wd, bd, out);
    // layer 2: h = relu(agg1) (stride 32) -> pooled + head (fused)
    layer_kernel<<<NN / 4, 256, 0, stream>>>(agg1, 32, 1, e, pair, cnt,
                                             Wk2, bk2, root2, b2,
                                             agg1, 1, pooled, ticket, Wd, bd, out);
}